// Round 5
// baseline (224.217 us; speedup 1.0000x reference)
//
#include <hip/hip_runtime.h>

#define CIN    256
#define COUT   256
#define PTOT   4096
#define BM     128
#define BN     128
#define BK     32
#define KSTEPS 8
#define LDSA   40   // A row stride in bf16 elems: 32 data + 8 pad -> 80 B rows
                    // 80*r mod 128 cycles all 8 16B-slots per 8 rows -> even bank
                    // spread for b128 reads and uint2 writes, no swizzle needed.

typedef __attribute__((ext_vector_type(8)))  short bfrag;
typedef __attribute__((ext_vector_type(16))) float f32x16;

union U4F { uint4 u; bfrag f; };

__device__ __forceinline__ unsigned int f2bf(float f) {
    unsigned int x = __float_as_uint(f);
    x += 0x7fffu + ((x >> 16) & 1u);   // round-to-nearest-even
    return x >> 16;
}

__device__ __forceinline__ f32x16 zero16() {
    f32x16 v;
    #pragma unroll
    for (int i = 0; i < 16; ++i) v[i] = 0.0f;
    return v;
}

__global__ __launch_bounds__(256, 4)
void selconv_mfma(const float* __restrict__ x,
                  const int*   __restrict__ classes,
                  const float* __restrict__ weight,
                  const float* __restrict__ bias,
                  float*       __restrict__ out)
{
    // A: bf16 [128 rows][40]      -> 10240 B per buffer
    // B: uint k-pair [16][128 px] ->  8192 B per buffer (low16 = even k, high16 = odd k)
    __shared__ __align__(16) unsigned short As[2][BM * LDSA];
    __shared__ __align__(16) unsigned int   Bs[2][(BK / 2) * BN];
    __shared__ float bias_s[BM];    // total 36.5 KB -> 4 blocks/CU

    // XCD-aware bijective swizzle (2048 % 8 == 0) + TWIN-PAIR ordering:
    // bit0 of the XCD-local index is the o-half, so the two blocks that share
    // an x pixel-tile (o0=0 / o0=128) dispatch 8 apart -> co-resident -> the
    // second one's x reads are L2/L3 hits. x costs ~134 MB HBM by construction
    // (R3's sample-major ordering ran the twins ~32 blocks apart -> x fetched
    // twice from HBM, FETCH_SIZE 310 MB).
    const int b     = blockIdx.x;
    const int xcd   = b & 7;
    const int local = b >> 3;                  // 0..255
    const int n     = xcd * 4 + (local >> 6);  // 0..31 (<=2 samples co-resident/XCD)
    const int o0    = (local & 1) * BM;        // twin bit
    const int p0    = ((local >> 1) & 31) * BN;

    const int tid  = threadIdx.x;
    const int lane = tid & 63;
    const int wid  = tid >> 6;                // 4 waves: 2x2 output grid
    const int wr   = wid >> 1;
    const int wc   = wid & 1;

    const int cls = classes[n];
    const float* Wn = weight + (size_t)cls * (COUT * CIN) + (size_t)o0 * CIN;
    const float* Xn = x   + (size_t)n * (CIN * PTOT) + p0;
    float*       On = out + (size_t)n * (COUT * PTOT) + (size_t)o0 * PTOT + p0;

    if (tid < BM) bias_s[tid] = bias[cls * COUT + o0 + tid];

    // staging maps
    const int a_row0 = tid >> 3;          // 0..31 (+32i) -> 128 rows, 8 lanes/row
    const int a_col  = (tid & 7) * 4;     // k offset within BK
    const int b_kp   = tid >> 5;          // k-pair row 0..7 (+8j)
    const int b_p4   = (tid & 31) * 4;    // 4 pixels; 32 lanes cover 128 contiguously

    float4 A0[4], A1[4];                  // two named prefetch sets (rule #20)
    float4 B0[4], B1[4];

    auto loadA = [&](float4 (&A)[4], int t) {
        const int k0 = t * BK;
        #pragma unroll
        for (int i = 0; i < 4; ++i)
            A[i] = *(const float4*)(Wn + (size_t)(a_row0 + 32 * i) * CIN + k0 + a_col);
    };
    auto loadB = [&](float4 (&B)[4], int t) {
        const int k0 = t * BK;
        #pragma unroll
        for (int j = 0; j < 2; ++j) {
            const int kr = k0 + 2 * (b_kp + 8 * j);
            B[j * 2 + 0] = *(const float4*)(Xn + (size_t)kr       * PTOT + b_p4);
            B[j * 2 + 1] = *(const float4*)(Xn + (size_t)(kr + 1) * PTOT + b_p4);
        }
    };
    auto writeT = [&](int buf, float4 (&A)[4], float4 (&B)[4]) {
        #pragma unroll
        for (int i = 0; i < 4; ++i) {
            const int row = a_row0 + 32 * i;
            uint2 w;
            w.x = f2bf(A[i].x) | (f2bf(A[i].y) << 16);
            w.y = f2bf(A[i].z) | (f2bf(A[i].w) << 16);
            *(uint2*)(&As[buf][row * LDSA + a_col]) = w;   // 8B, even bank spread
        }
        #pragma unroll
        for (int j = 0; j < 2; ++j) {
            const int kp = b_kp + 8 * j;
            const float4 e = B[j * 2 + 0];   // even k row
            const float4 o = B[j * 2 + 1];   // odd  k row
            uint4 w;
            w.x = f2bf(e.x) | (f2bf(o.x) << 16);
            w.y = f2bf(e.y) | (f2bf(o.y) << 16);
            w.z = f2bf(e.z) | (f2bf(o.z) << 16);
            w.w = f2bf(e.w) | (f2bf(o.w) << 16);
            *(uint4*)(&Bs[buf][kp * BN + b_p4]) = w;       // 16B contiguous, conflict-free
        }
    };

    const int fr  = lane & 31;            // row/col within 32x32 frag
    const int fg8 = (lane >> 5) * 8;      // 8 consecutive k per lane; identical
                                          // mapping for A and B -> hw k-perm cancels
    f32x16 acc00 = zero16(), acc01 = zero16(), acc10 = zero16(), acc11 = zero16();

    auto mfma_step = [&](int buf) {
        const unsigned short* Ab = As[buf];
        const unsigned int*   Bb = Bs[buf];
        const int rowA0 = wr * 64 + fr;
        const int pB0   = wc * 64 + fr;
        #pragma unroll
        for (int s = 0; s < 2; ++s) {
            const int kof = s * 16 + fg8;
            const int kp0 = kof >> 1;     // k-pair row base (4 consecutive rows)
            bfrag a0 = *(const bfrag*)(&Ab[(rowA0     ) * LDSA + kof]);
            bfrag a1 = *(const bfrag*)(&Ab[(rowA0 + 32) * LDSA + kof]);
            U4F ub0, ub1;
            ub0.u.x = Bb[(kp0 + 0) * BN + pB0];
            ub0.u.y = Bb[(kp0 + 1) * BN + pB0];
            ub0.u.z = Bb[(kp0 + 2) * BN + pB0];
            ub0.u.w = Bb[(kp0 + 3) * BN + pB0];
            ub1.u.x = Bb[(kp0 + 0) * BN + pB0 + 32];
            ub1.u.y = Bb[(kp0 + 1) * BN + pB0 + 32];
            ub1.u.z = Bb[(kp0 + 2) * BN + pB0 + 32];
            ub1.u.w = Bb[(kp0 + 3) * BN + pB0 + 32];
            acc00 = __builtin_amdgcn_mfma_f32_32x32x16_bf16(a0, ub0.f, acc00, 0, 0, 0);
            acc01 = __builtin_amdgcn_mfma_f32_32x32x16_bf16(a0, ub1.f, acc01, 0, 0, 0);
            acc10 = __builtin_amdgcn_mfma_f32_32x32x16_bf16(a1, ub0.f, acc10, 0, 0, 0);
            acc11 = __builtin_amdgcn_mfma_f32_32x32x16_bf16(a1, ub1.f, acc11, 0, 0, 0);
        }
    };

    // ---- 2-deep pipeline: loads for t+2 issued at step t ----
    loadA(A0, 0); loadB(B0, 0);
    loadA(A1, 1); loadB(B1, 1);
    writeT(0, A0, B0);
    __syncthreads();

    #pragma unroll
    for (int t = 0; t < KSTEPS; t += 2) {
        if (t + 2 < KSTEPS) { loadA(A0, t + 2); loadB(B0, t + 2); }
        mfma_step(0);
        writeT(1, A1, B1);                 // tile t+1 (regs loaded one step ago)
        __syncthreads();
        if (t + 3 < KSTEPS) { loadA(A1, t + 3); loadB(B1, t + 3); }
        mfma_step(1);
        if (t + 2 < KSTEPS) { writeT(0, A0, B0); __syncthreads(); }
    }

    // epilogue: D col = lane&31, row = (reg&3) + 8*(reg>>2) + 4*(lane>>5)
    const int col = lane & 31;
    const int rh  = (lane >> 5) * 4;

    auto store_frag = [&](f32x16 a, int mi, int nj) {
        const int ob = wr * 64 + mi * 32;
        const int pc = wc * 64 + nj * 32 + col;
        #pragma unroll
        for (int r = 0; r < 16; ++r) {
            const int row = (r & 3) + 8 * (r >> 2) + rh;
            const int o   = ob + row;
            On[(size_t)o * PTOT + pc] = a[r] + bias_s[o];
        }
    };
    store_frag(acc00, 0, 0);
    store_frag(acc01, 0, 1);
    store_frag(acc10, 1, 0);
    store_frag(acc11, 1, 1);
}

extern "C" void kernel_launch(void* const* d_in, const int* in_sizes, int n_in,
                              void* d_out, int out_size, void* d_ws, size_t ws_size,
                              hipStream_t stream) {
    const float* x       = (const float*)d_in[0];
    const int*   classes = (const int*)d_in[1];
    const float* weight  = (const float*)d_in[2];
    const float* bias    = (const float*)d_in[3];
    float*       out     = (float*)d_out;

    const int grid = 32 * (COUT / BM) * (PTOT / BN);  // 2048
    selconv_mfma<<<grid, 256, 0, stream>>>(x, classes, weight, bias, out);
}

// Round 6
// 63.912 us; speedup vs baseline: 3.5082x; 3.5082x over previous
//
#include <hip/hip_runtime.h>

#define CIN    256
#define COUT   256
#define PTOT   4096
#define BM     128
#define BN     128
#define BK     32
#define KSTEPS 8
#define LDSA   40   // A row stride in bf16 elems: 32 data + 8 pad -> 80 B rows
                    // 80*r mod 128 cycles all 8 16B-slots per 8 rows -> even bank
                    // spread for b128 reads and uint2 writes, no swizzle needed.
#define BPAD   512  // +2KB per B buffer: LDS 37.4 -> 41.5 KB => max 3 blocks/CU.
                    // R3/R5 showed 4 blk/CU (1024 co-resident blocks) thrashes
                    // L2+L3: fetch 258-310 MB, dur 225 us. 3 blk/CU (R2/R4) is
                    // the non-thrashing regime: fetch 70-102 MB.

typedef __attribute__((ext_vector_type(8)))  short bfrag;
typedef __attribute__((ext_vector_type(16))) float f32x16;

union U4F { uint4 u; bfrag f; };

__device__ __forceinline__ unsigned int f2bf(float f) {
    unsigned int x = __float_as_uint(f);
    x += 0x7fffu + ((x >> 16) & 1u);   // round-to-nearest-even
    return x >> 16;
}

__device__ __forceinline__ f32x16 zero16() {
    f32x16 v;
    #pragma unroll
    for (int i = 0; i < 16; ++i) v[i] = 0.0f;
    return v;
}

__global__ __launch_bounds__(256, 3)
void selconv_mfma(const float* __restrict__ x,
                  const int*   __restrict__ classes,
                  const float* __restrict__ weight,
                  const float* __restrict__ bias,
                  float*       __restrict__ out)
{
    // A: bf16 [128 rows][40]      -> 10240 B per buffer
    // B: uint k-pair [16][128 px] ->  8192 B (+2KB pad) per buffer
    __shared__ __align__(16) unsigned short As[2][BM * LDSA];
    __shared__ __align__(16) unsigned int   Bs[2][(BK / 2) * BN + BPAD];
    __shared__ float bias_s[BM];    // total 41.5 KB -> exactly 3 blocks/CU

    // XCD-aware bijective swizzle (2048 % 8 == 0), twin (o-half) in bit 0 so
    // the two blocks sharing an x pixel-tile are always co-resident.
    const int b     = blockIdx.x;
    const int xcd   = b & 7;
    const int local = b >> 3;                  // 0..255
    const int n     = xcd * 4 + (local >> 6);  // 0..31
    const int o0    = (local & 1) * BM;        // twin bit
    const int p0    = ((local >> 1) & 31) * BN;

    const int tid  = threadIdx.x;
    const int lane = tid & 63;
    const int wid  = tid >> 6;                // 4 waves: 2x2 output grid
    const int wr   = wid >> 1;
    const int wc   = wid & 1;

    const int cls = classes[n];
    const float* Wn = weight + (size_t)cls * (COUT * CIN) + (size_t)o0 * CIN;
    const float* Xn = x   + (size_t)n * (CIN * PTOT) + p0;
    float*       On = out + (size_t)n * (COUT * PTOT) + (size_t)o0 * PTOT + p0;

    if (tid < BM) bias_s[tid] = bias[cls * COUT + o0 + tid];

    // staging maps
    const int a_row0 = tid >> 3;          // 0..31 (+32i) -> 128 rows, 8 lanes/row
    const int a_col  = (tid & 7) * 4;     // k offset within BK
    const int b_kp   = tid >> 5;          // k-pair row 0..7 (+8j)
    const int b_p4   = (tid & 31) * 4;    // 4 pixels; 32 lanes cover 128 contiguously

    float4 A0[4], A1[4];                  // two named prefetch sets (rule #20)
    float4 B0[4], B1[4];

    auto loadA = [&](float4 (&A)[4], int t) {
        const int k0 = t * BK;
        #pragma unroll
        for (int i = 0; i < 4; ++i)
            A[i] = *(const float4*)(Wn + (size_t)(a_row0 + 32 * i) * CIN + k0 + a_col);
    };
    auto loadB = [&](float4 (&B)[4], int t) {
        const int k0 = t * BK;
        #pragma unroll
        for (int j = 0; j < 2; ++j) {
            const int kr = k0 + 2 * (b_kp + 8 * j);
            B[j * 2 + 0] = *(const float4*)(Xn + (size_t)kr       * PTOT + b_p4);
            B[j * 2 + 1] = *(const float4*)(Xn + (size_t)(kr + 1) * PTOT + b_p4);
        }
    };
    auto writeT = [&](int buf, float4 (&A)[4], float4 (&B)[4]) {
        #pragma unroll
        for (int i = 0; i < 4; ++i) {
            const int row = a_row0 + 32 * i;
            uint2 w;
            w.x = f2bf(A[i].x) | (f2bf(A[i].y) << 16);
            w.y = f2bf(A[i].z) | (f2bf(A[i].w) << 16);
            *(uint2*)(&As[buf][row * LDSA + a_col]) = w;   // 8B, even bank spread
        }
        #pragma unroll
        for (int j = 0; j < 2; ++j) {
            const int kp = b_kp + 8 * j;
            const float4 e = B[j * 2 + 0];   // even k row
            const float4 o = B[j * 2 + 1];   // odd  k row
            uint4 w;
            w.x = f2bf(e.x) | (f2bf(o.x) << 16);
            w.y = f2bf(e.y) | (f2bf(o.y) << 16);
            w.z = f2bf(e.z) | (f2bf(o.z) << 16);
            w.w = f2bf(e.w) | (f2bf(o.w) << 16);
            *(uint4*)(&Bs[buf][kp * BN + b_p4]) = w;       // 16B contiguous, conflict-free
        }
    };

    const int fr  = lane & 31;            // row/col within 32x32 frag
    const int fg8 = (lane >> 5) * 8;      // 8 consecutive k per lane; identical
                                          // mapping for A and B -> hw k-perm cancels
    f32x16 acc00 = zero16(), acc01 = zero16(), acc10 = zero16(), acc11 = zero16();

    auto mfma_step = [&](int buf) {
        const unsigned short* Ab = As[buf];
        const unsigned int*   Bb = Bs[buf];
        const int rowA0 = wr * 64 + fr;
        const int pB0   = wc * 64 + fr;
        #pragma unroll
        for (int s = 0; s < 2; ++s) {
            const int kof = s * 16 + fg8;
            const int kp0 = kof >> 1;     // k-pair row base (4 consecutive rows)
            bfrag a0 = *(const bfrag*)(&Ab[(rowA0     ) * LDSA + kof]);
            bfrag a1 = *(const bfrag*)(&Ab[(rowA0 + 32) * LDSA + kof]);
            U4F ub0, ub1;
            ub0.u.x = Bb[(kp0 + 0) * BN + pB0];
            ub0.u.y = Bb[(kp0 + 1) * BN + pB0];
            ub0.u.z = Bb[(kp0 + 2) * BN + pB0];
            ub0.u.w = Bb[(kp0 + 3) * BN + pB0];
            ub1.u.x = Bb[(kp0 + 0) * BN + pB0 + 32];
            ub1.u.y = Bb[(kp0 + 1) * BN + pB0 + 32];
            ub1.u.z = Bb[(kp0 + 2) * BN + pB0 + 32];
            ub1.u.w = Bb[(kp0 + 3) * BN + pB0 + 32];
            acc00 = __builtin_amdgcn_mfma_f32_32x32x16_bf16(a0, ub0.f, acc00, 0, 0, 0);
            acc01 = __builtin_amdgcn_mfma_f32_32x32x16_bf16(a0, ub1.f, acc01, 0, 0, 0);
            acc10 = __builtin_amdgcn_mfma_f32_32x32x16_bf16(a1, ub0.f, acc10, 0, 0, 0);
            acc11 = __builtin_amdgcn_mfma_f32_32x32x16_bf16(a1, ub1.f, acc11, 0, 0, 0);
        }
    };

    // ---- 2-deep pipeline: loads for t+2 issued at step t ----
    loadA(A0, 0); loadB(B0, 0);
    loadA(A1, 1); loadB(B1, 1);
    writeT(0, A0, B0);
    __syncthreads();

    #pragma unroll
    for (int t = 0; t < KSTEPS; t += 2) {
        if (t + 2 < KSTEPS) { loadA(A0, t + 2); loadB(B0, t + 2); }
        mfma_step(0);
        writeT(1, A1, B1);                 // tile t+1 (regs loaded one step ago)
        __syncthreads();
        if (t + 3 < KSTEPS) { loadA(A1, t + 3); loadB(B1, t + 3); }
        mfma_step(1);
        if (t + 2 < KSTEPS) { writeT(0, A0, B0); __syncthreads(); }
    }

    // epilogue: D col = lane&31, row = (reg&3) + 8*(reg>>2) + 4*(lane>>5)
    const int col = lane & 31;
    const int rh  = (lane >> 5) * 4;

    auto store_frag = [&](f32x16 a, int mi, int nj) {
        const int ob = wr * 64 + mi * 32;
        const int pc = wc * 64 + nj * 32 + col;
        #pragma unroll
        for (int r = 0; r < 16; ++r) {
            const int row = (r & 3) + 8 * (r >> 2) + rh;
            const int o   = ob + row;
            On[(size_t)o * PTOT + pc] = a[r] + bias_s[o];
        }
    };
    store_frag(acc00, 0, 0);
    store_frag(acc01, 0, 1);
    store_frag(acc10, 1, 0);
    store_frag(acc11, 1, 1);
}

extern "C" void kernel_launch(void* const* d_in, const int* in_sizes, int n_in,
                              void* d_out, int out_size, void* d_ws, size_t ws_size,
                              hipStream_t stream) {
    const float* x       = (const float*)d_in[0];
    const int*   classes = (const int*)d_in[1];
    const float* weight  = (const float*)d_in[2];
    const float* bias    = (const float*)d_in[3];
    float*       out     = (float*)d_out;

    const int grid = 32 * (COUT / BM) * (PTOT / BN);  // 2048
    selconv_mfma<<<grid, 256, 0, stream>>>(x, classes, weight, bias, out);
}

// Round 7
// 62.905 us; speedup vs baseline: 3.5644x; 1.0160x over previous
//
#include <hip/hip_runtime.h>

#define CIN    256
#define COUT   256
#define PTOT   4096
#define BM     128
#define BN     128
#define BK     32
#define KSTEPS 8
#define LDSA   40   // A row stride in bf16 elems: 32 data + 8 pad -> 80 B rows
                    // 80*r mod 128 cycles all 8 16B-slots per 8 rows -> even bank
                    // spread for b128 reads and uint2 writes, no swizzle needed.
#define BPAD   512  // +2KB per B buffer: LDS -> 41.5 KB => exactly 3 blocks/CU.
                    // 4 blk/CU thrashes L2+L3 (R3/R5: fetch 258-310 MB, 225 us).

typedef __attribute__((ext_vector_type(8)))  short bfrag;
typedef __attribute__((ext_vector_type(16))) float f32x16;

union U4F { uint4 u; bfrag f; };

__device__ __forceinline__ unsigned int f2bf(float f) {
    unsigned int x = __float_as_uint(f);
    x += 0x7fffu + ((x >> 16) & 1u);   // round-to-nearest-even
    return x >> 16;
}

__device__ __forceinline__ f32x16 zero16() {
    f32x16 v;
    #pragma unroll
    for (int i = 0; i < 16; ++i) v[i] = 0.0f;
    return v;
}

// T4 counted barrier: __syncthreads() compiles to `s_waitcnt vmcnt(0)
// lgkmcnt(0); s_barrier`, draining the global-load prefetch queue every
// K-step (all waves convoy; in-flight bytes -> 0; Little's-law starved).
// This kernel only needs LDS visibility at the barrier: lgkmcnt(0) covers
// our ds_writes (RAW for other waves) and our ds_reads of the buffer about
// to be overwritten (WAR). Global loads land in private registers — the
// compiler emits its own COUNTED vmcnt before the registers are consumed,
// so prefetched tiles stay in flight ACROSS the barrier.
__device__ __forceinline__ void lds_barrier() {
    asm volatile("s_waitcnt lgkmcnt(0)" ::: "memory");
    __builtin_amdgcn_s_barrier();
    asm volatile("" ::: "memory");   // fence compiler reordering around barrier
}

__global__ __launch_bounds__(256, 3)
void selconv_mfma(const float* __restrict__ x,
                  const int*   __restrict__ classes,
                  const float* __restrict__ weight,
                  const float* __restrict__ bias,
                  float*       __restrict__ out)
{
    // A: bf16 [128 rows][40]      -> 10240 B per buffer
    // B: uint k-pair [16][128 px] ->  8192 B (+2KB pad) per buffer
    __shared__ __align__(16) unsigned short As[2][BM * LDSA];
    __shared__ __align__(16) unsigned int   Bs[2][(BK / 2) * BN + BPAD];
    __shared__ float bias_s[BM];    // total 41.5 KB -> exactly 3 blocks/CU

    // XCD-aware bijective swizzle (2048 % 8 == 0), twin (o-half) in bit 0 so
    // the two blocks sharing an x pixel-tile are always co-resident.
    const int b     = blockIdx.x;
    const int xcd   = b & 7;
    const int local = b >> 3;                  // 0..255
    const int n     = xcd * 4 + (local >> 6);  // 0..31
    const int o0    = (local & 1) * BM;        // twin bit
    const int p0    = ((local >> 1) & 31) * BN;

    const int tid  = threadIdx.x;
    const int lane = tid & 63;
    const int wid  = tid >> 6;                // 4 waves: 2x2 output grid
    const int wr   = wid >> 1;
    const int wc   = wid & 1;

    const int cls = classes[n];
    const float* Wn = weight + (size_t)cls * (COUT * CIN) + (size_t)o0 * CIN;
    const float* Xn = x   + (size_t)n * (CIN * PTOT) + p0;
    float*       On = out + (size_t)n * (COUT * PTOT) + (size_t)o0 * PTOT + p0;

    if (tid < BM) bias_s[tid] = bias[cls * COUT + o0 + tid];

    // staging maps
    const int a_row0 = tid >> 3;          // 0..31 (+32i) -> 128 rows, 8 lanes/row
    const int a_col  = (tid & 7) * 4;     // k offset within BK
    const int b_kp   = tid >> 5;          // k-pair row 0..7 (+8j)
    const int b_p4   = (tid & 31) * 4;    // 4 pixels; 32 lanes cover 128 contiguously

    float4 A0[4], A1[4];                  // two named prefetch sets (rule #20)
    float4 B0[4], B1[4];

    auto loadA = [&](float4 (&A)[4], int t) {
        const int k0 = t * BK;
        #pragma unroll
        for (int i = 0; i < 4; ++i)
            A[i] = *(const float4*)(Wn + (size_t)(a_row0 + 32 * i) * CIN + k0 + a_col);
    };
    auto loadB = [&](float4 (&B)[4], int t) {
        const int k0 = t * BK;
        #pragma unroll
        for (int j = 0; j < 2; ++j) {
            const int kr = k0 + 2 * (b_kp + 8 * j);
            B[j * 2 + 0] = *(const float4*)(Xn + (size_t)kr       * PTOT + b_p4);
            B[j * 2 + 1] = *(const float4*)(Xn + (size_t)(kr + 1) * PTOT + b_p4);
        }
    };
    auto writeT = [&](int buf, float4 (&A)[4], float4 (&B)[4]) {
        #pragma unroll
        for (int i = 0; i < 4; ++i) {
            const int row = a_row0 + 32 * i;
            uint2 w;
            w.x = f2bf(A[i].x) | (f2bf(A[i].y) << 16);
            w.y = f2bf(A[i].z) | (f2bf(A[i].w) << 16);
            *(uint2*)(&As[buf][row * LDSA + a_col]) = w;   // 8B, even bank spread
        }
        #pragma unroll
        for (int j = 0; j < 2; ++j) {
            const int kp = b_kp + 8 * j;
            const float4 e = B[j * 2 + 0];   // even k row
            const float4 o = B[j * 2 + 1];   // odd  k row
            uint4 w;
            w.x = f2bf(e.x) | (f2bf(o.x) << 16);
            w.y = f2bf(e.y) | (f2bf(o.y) << 16);
            w.z = f2bf(e.z) | (f2bf(o.z) << 16);
            w.w = f2bf(e.w) | (f2bf(o.w) << 16);
            *(uint4*)(&Bs[buf][kp * BN + b_p4]) = w;       // 16B contiguous, conflict-free
        }
    };

    const int fr  = lane & 31;            // row/col within 32x32 frag
    const int fg8 = (lane >> 5) * 8;      // 8 consecutive k per lane; identical
                                          // mapping for A and B -> hw k-perm cancels
    f32x16 acc00 = zero16(), acc01 = zero16(), acc10 = zero16(), acc11 = zero16();

    auto mfma_step = [&](int buf) {
        const unsigned short* Ab = As[buf];
        const unsigned int*   Bb = Bs[buf];
        const int rowA0 = wr * 64 + fr;
        const int pB0   = wc * 64 + fr;
        #pragma unroll
        for (int s = 0; s < 2; ++s) {
            const int kof = s * 16 + fg8;
            const int kp0 = kof >> 1;     // k-pair row base (4 consecutive rows)
            bfrag a0 = *(const bfrag*)(&Ab[(rowA0     ) * LDSA + kof]);
            bfrag a1 = *(const bfrag*)(&Ab[(rowA0 + 32) * LDSA + kof]);
            U4F ub0, ub1;
            ub0.u.x = Bb[(kp0 + 0) * BN + pB0];
            ub0.u.y = Bb[(kp0 + 1) * BN + pB0];
            ub0.u.z = Bb[(kp0 + 2) * BN + pB0];
            ub0.u.w = Bb[(kp0 + 3) * BN + pB0];
            ub1.u.x = Bb[(kp0 + 0) * BN + pB0 + 32];
            ub1.u.y = Bb[(kp0 + 1) * BN + pB0 + 32];
            ub1.u.z = Bb[(kp0 + 2) * BN + pB0 + 32];
            ub1.u.w = Bb[(kp0 + 3) * BN + pB0 + 32];
            acc00 = __builtin_amdgcn_mfma_f32_32x32x16_bf16(a0, ub0.f, acc00, 0, 0, 0);
            acc01 = __builtin_amdgcn_mfma_f32_32x32x16_bf16(a0, ub1.f, acc01, 0, 0, 0);
            acc10 = __builtin_amdgcn_mfma_f32_32x32x16_bf16(a1, ub0.f, acc10, 0, 0, 0);
            acc11 = __builtin_amdgcn_mfma_f32_32x32x16_bf16(a1, ub1.f, acc11, 0, 0, 0);
        }
    };

    // ---- 2-deep pipeline: loads for t+2 issued at step t; loads survive
    // ---- the (counted) barrier -> continuous HBM MLP.
    loadA(A0, 0); loadB(B0, 0);
    loadA(A1, 1); loadB(B1, 1);
    writeT(0, A0, B0);
    lds_barrier();

    #pragma unroll
    for (int t = 0; t < KSTEPS; t += 2) {
        if (t + 2 < KSTEPS) { loadA(A0, t + 2); loadB(B0, t + 2); }
        mfma_step(0);
        writeT(1, A1, B1);                 // tile t+1 (regs loaded one step ago)
        lds_barrier();
        if (t + 3 < KSTEPS) { loadA(A1, t + 3); loadB(B1, t + 3); }
        mfma_step(1);
        if (t + 2 < KSTEPS) { writeT(0, A0, B0); lds_barrier(); }
    }

    // epilogue: D col = lane&31, row = (reg&3) + 8*(reg>>2) + 4*(lane>>5)
    const int col = lane & 31;
    const int rh  = (lane >> 5) * 4;

    auto store_frag = [&](f32x16 a, int mi, int nj) {
        const int ob = wr * 64 + mi * 32;
        const int pc = wc * 64 + nj * 32 + col;
        #pragma unroll
        for (int r = 0; r < 16; ++r) {
            const int row = (r & 3) + 8 * (r >> 2) + rh;
            const int o   = ob + row;
            On[(size_t)o * PTOT + pc] = a[r] + bias_s[o];
        }
    };
    store_frag(acc00, 0, 0);
    store_frag(acc01, 0, 1);
    store_frag(acc10, 1, 0);
    store_frag(acc11, 1, 1);
}

extern "C" void kernel_launch(void* const* d_in, const int* in_sizes, int n_in,
                              void* d_out, int out_size, void* d_ws, size_t ws_size,
                              hipStream_t stream) {
    const float* x       = (const float*)d_in[0];
    const int*   classes = (const int*)d_in[1];
    const float* weight  = (const float*)d_in[2];
    const float* bias    = (const float*)d_in[3];
    float*       out     = (float*)d_out;

    const int grid = 32 * (COUT / BM) * (PTOT / BN);  // 2048
    selconv_mfma<<<grid, 256, 0, stream>>>(x, classes, weight, bias, out);
}